// Round 8
// baseline (17.572 us; speedup 1.0000x reference)
//
#include <hip/hip_runtime.h>
#include <math.h>

#define B_   64
#define O_   512
#define N_   784
#define M_   1024
#define BIGV 1e10f

// Single kernel, no workspace. Block = (b, quarter q of 128 o's), 512 threads.
//  A: stable min/argmin + max of e = exp(1.79*x[b,:])  (block-local reduce)
//  B: flag[o] = (2*rowmax(w[o,:]) > 1) for this block's 128 rows.
//     ONE WAVE PER ROW (contiguous float4, 1KB/instr coalesced) x 16 rows/wave.
//     Redundant across b (64x) but L2-resident and fully parallel (~100MB L2).
//     Only flagged o can EVER satisfy ws_sum > 1 at j < N:
//       ws = RN(wg[j]+wg[j-1]) <= RN(m+m) = 2m (RN monotone, 2m exact),
//     so 2m <= 1 => cond2 false for all j < N (and w0 > 1 false at j = 0).
//  C: unflagged o: index = N if BIG < smax else 0  ->
//       out = BIG < smax ? BIG : s0*w0 / clip(w0-1, 1e-10, BIG),  w0 = w[o,i0]
//  D: (cold, block-uniform) flagged o: bitonic sort in LDS + faithful scan.
__global__ __launch_bounds__(512) void snn_one(const float* __restrict__ x,
                                               const float* __restrict__ w,
                                               float* __restrict__ out)
{
    __shared__ float wmn[8];
    __shared__ int   wmi[8];
    __shared__ float wmx[8];
    __shared__ int   flags[128];
    __shared__ float sk[M_];          // cold path only
    __shared__ int   sv[M_];          // cold path only

    const int tid   = threadIdx.x;
    const int b     = blockIdx.x >> 2;
    const int q     = blockIdx.x & 3;
    const int obase = q * 128;

    // ---------------- phase A: e-row reduce ----------------
    float mn = __builtin_inff(); int mni = 0; float mx = 0.0f;
    for (int i = tid; i < N_; i += 512) {
        float v = expf(x[b * N_ + i] * 1.79f);
        if (v < mn) { mn = v; mni = i; }          // ascending i per thread
        mx = fmaxf(mx, v);
    }
    #pragma unroll
    for (int d = 1; d < 64; d <<= 1) {
        float omn = __shfl_xor(mn, d);
        int   omi = __shfl_xor(mni, d);
        float omx = __shfl_xor(mx, d);
        if (omn < mn || (omn == mn && omi < mni)) { mn = omn; mni = omi; }
        mx = fmaxf(mx, omx);
    }
    if ((tid & 63) == 0) { wmn[tid >> 6] = mn; wmi[tid >> 6] = mni; wmx[tid >> 6] = mx; }

    // ---------------- phase B: flags, one wave per row ----------------
    {
        const int wv   = tid >> 6;                // wave 0..7 -> rows wv*16..wv*16+15
        const int lane = tid & 63;
        #pragma unroll
        for (int rr = 0; rr < 16; ++rr) {
            const int row = obase + wv * 16 + rr;
            const float4* wr = (const float4*)(w + (size_t)row * N_);
            float m = 0.0f;
            #pragma unroll
            for (int it = 0; it < 4; ++it) {
                int idx = lane + it * 64;         // 196 float4s per row
                if (idx < 196) {
                    float4 v = wr[idx];           // 1KB contiguous per wave instr
                    m = fmaxf(m, fmaxf(fmaxf(v.x, v.y), fmaxf(v.z, v.w)));
                }
            }
            #pragma unroll
            for (int d = 1; d < 64; d <<= 1)
                m = fmaxf(m, __shfl_xor(m, d));
            if (lane == 0) flags[wv * 16 + rr] = (m + m > 1.0f) ? 1 : 0;
        }
    }
    __syncthreads();                               // flags + wmn/wmi/wmx visible
    int anyflag = __syncthreads_or(tid < 128 ? flags[tid] : 0);

    float s0 = wmn[0]; int i0 = wmi[0]; float smax = wmx[0];
    #pragma unroll
    for (int k = 1; k < 8; ++k) {                 // uniform, LDS broadcast
        float v = wmn[k]; int vi = wmi[k];
        if (v < s0 || (v == s0 && vi < i0)) { s0 = v; i0 = vi; }
        smax = fmaxf(smax, wmx[k]);
    }

    // ---------------- phase C: fast path ----------------
    if (tid < 128 && !flags[tid]) {
        const int o  = obase + tid;
        float w0   = w[(size_t)o * N_ + i0];      // one gather per output
        float mul0 = s0 * w0;
        float den0 = fminf(fmaxf(w0 - 1.0f, 1e-10f), BIGV);
        float oa0  = mul0 / den0;
        out[b * O_ + o] = (BIGV < smax) ? BIGV : oa0;
    }

    // ---------------- phase D: cold exact fallback ----------------
    if (anyflag) {
        for (int i = tid; i < M_; i += 512) {
            sk[i] = (i < N_) ? expf(x[b * N_ + i] * 1.79f) : __builtin_inff();
            sv[i] = i;
        }
        __syncthreads();
        for (int k = 2; k <= M_; k <<= 1) {
            for (int j = k >> 1; j > 0; j >>= 1) {
                int i = ((tid & ~(j - 1)) << 1) | (tid & (j - 1));
                int p = i | j;
                float ki = sk[i], kp = sk[p];
                int   vi = sv[i], vp = sv[p];
                bool gt = (ki > kp) || (ki == kp && vi > vp);
                bool up = ((i & k) == 0);
                if (gt == up) { sk[i] = kp; sk[p] = ki; sv[i] = vp; sv[p] = vi; }
                __syncthreads();
            }
        }
        if (tid < 128 && flags[tid]) {
            const int o = obase + tid;
            const float* wrow = w + (size_t)o * N_;
            float w0   = wrow[sv[0]];
            float mul0 = sk[0] * w0;
            float den0 = fminf(fmaxf(w0 - 1.0f, 1e-10f), BIGV);
            float oa0  = mul0 / den0;
            bool found = (oa0 < __builtin_inff()) && (w0 > 1.0f);
            float res  = oa0;
            float wprev = w0, mulprev = mul0;
            for (int j = 1; j < N_; ++j) {
                float wj   = wrow[sv[j]];
                float sj   = sk[j];
                float mulj = sj * wj;
                float ws   = wj + wprev;
                float wim  = mulj + mulprev;
                float den  = fminf(fmaxf(ws - 1.0f, 1e-10f), BIGV);
                float oa   = wim / den;
                bool cond  = (oa < sk[j - 1]) && (ws > 1.0f);
                if (cond && !found) { res = oa; found = true; }
                wprev = wj; mulprev = mulj;
            }
            if (!found && BIGV < smax) res = BIGV;
            out[b * O_ + o] = res;
        }
    }
}

extern "C" void kernel_launch(void* const* d_in, const int* in_sizes, int n_in,
                              void* d_out, int out_size, void* d_ws, size_t ws_size,
                              hipStream_t stream)
{
    const float* x = (const float*)d_in[0];   // [B, N]
    const float* w = (const float*)d_in[1];   // [O, N]
    float* out = (float*)d_out;               // [B, O]

    hipLaunchKernelGGL(snn_one, dim3(B_ * 4), dim3(512), 0, stream, x, w, out);
}

// Round 9
// 11.325 us; speedup vs baseline: 1.5516x; 1.5516x over previous
//
#include <hip/hip_runtime.h>
#include <math.h>

#define B_   64
#define O_   512
#define N_   784
#define M_   1024
#define BIGV 1e10f

// ---------------------------------------------------------------------------
// K1 (heterogeneous grid, 128 blocks x 512 thr):
//  blocks 0..63   : flags. One wave per w-row (contiguous float4, 1KB/instr),
//                   8 rows per block. flag[o] = (2*rowmax(w[o,:]) > 1).
//                   Only flagged o can EVER satisfy ws_sum > 1 at j < N:
//                   ws = RN(wg[j]+wg[j-1]) <= RN(m+m) = 2m (RN monotone,
//                   2m exact), so 2m <= 1 => cond2 false for all j < N.
//  blocks 64..127 : per-b stats over e = exp(1.79*x[b,:]):
//                   s0 = min (stable argmin i0), smax = max.
// ---------------------------------------------------------------------------
__global__ __launch_bounds__(512) void snn_prep(const float* __restrict__ x,
                                                const float* __restrict__ w,
                                                int* __restrict__ flag,
                                                float* __restrict__ s0_g,
                                                int* __restrict__ i0_g,
                                                float* __restrict__ smax_g)
{
    const int tid = threadIdx.x;

    if (blockIdx.x < 64) {
        // ---- flags: wave wv handles row bid*8 + wv ----
        const int row  = blockIdx.x * 8 + (tid >> 6);
        const int lane = tid & 63;
        const float4* wr = (const float4*)(w + (size_t)row * N_);
        float m = 0.0f;
        #pragma unroll
        for (int it = 0; it < 4; ++it) {
            int idx = lane + it * 64;             // 196 float4s per row
            if (idx < 196) {
                float4 v = wr[idx];               // 1KB contiguous per wave instr
                m = fmaxf(m, fmaxf(fmaxf(v.x, v.y), fmaxf(v.z, v.w)));
            }
        }
        #pragma unroll
        for (int d = 1; d < 64; d <<= 1)
            m = fmaxf(m, __shfl_xor(m, d));
        if (lane == 0) flag[row] = (m + m > 1.0f) ? 1 : 0;
        return;
    }

    // ---- per-b stats ----
    __shared__ float wmn[8];
    __shared__ int   wmi[8];
    __shared__ float wmx[8];
    const int b = blockIdx.x - 64;

    float mn = __builtin_inff(); int mni = 0; float mx = 0.0f;
    for (int i = tid; i < N_; i += 512) {
        float v = expf(x[b * N_ + i] * 1.79f);
        if (v < mn) { mn = v; mni = i; }          // ascending i per thread
        mx = fmaxf(mx, v);
    }
    #pragma unroll
    for (int d = 1; d < 64; d <<= 1) {
        float omn = __shfl_xor(mn, d);
        int   omi = __shfl_xor(mni, d);
        float omx = __shfl_xor(mx, d);
        if (omn < mn || (omn == mn && omi < mni)) { mn = omn; mni = omi; }
        mx = fmaxf(mx, omx);
    }
    if ((tid & 63) == 0) { wmn[tid >> 6] = mn; wmi[tid >> 6] = mni; wmx[tid >> 6] = mx; }
    __syncthreads();
    if (tid == 0) {
        float s0 = wmn[0]; int i0 = wmi[0]; float smax = wmx[0];
        #pragma unroll
        for (int k = 1; k < 8; ++k) {
            float v = wmn[k]; int vi = wmi[k];
            if (v < s0 || (v == s0 && vi < i0)) { s0 = v; i0 = vi; }
            smax = fmaxf(smax, wmx[k]);
        }
        s0_g[b] = s0; i0_g[b] = i0; smax_g[b] = smax;
    }
}

// ---------------------------------------------------------------------------
// K2: block = b, thread = o (512). Fast path (unflagged o):
//   index = N if BIG < smax else 0  ->
//   out = BIG < smax ? BIG : s0*w0 / clip(w0-1, 1e-10, BIG),  w0 = w[o, i0].
// Cold exact path (block-uniform, only if some o flagged): bitonic sort of
// the e-row in LDS + faithful first-hit scan for flagged o's.
// ---------------------------------------------------------------------------
__global__ __launch_bounds__(512) void snn_out(const float* __restrict__ x,
                                               const float* __restrict__ w,
                                               const int* __restrict__ flag,
                                               const float* __restrict__ s0_g,
                                               const int* __restrict__ i0_g,
                                               const float* __restrict__ smax_g,
                                               float* __restrict__ out)
{
    __shared__ float sk[M_];          // cold path only
    __shared__ int   sv[M_];          // cold path only

    const int tid = threadIdx.x;      // == o
    const int b   = blockIdx.x;

    const float s0   = s0_g[b];       // uniform (scalar) loads
    const int   i0   = i0_g[b];
    const float smax = smax_g[b];

    const int fl = flag[tid];         // coalesced 2KB
    const int anyflag = __syncthreads_or(fl);

    if (!fl) {
        float w0   = w[(size_t)tid * N_ + i0];    // one gather per output
        float mul0 = s0 * w0;
        float den0 = fminf(fmaxf(w0 - 1.0f, 1e-10f), BIGV);
        float oa0  = mul0 / den0;
        out[b * O_ + tid] = (BIGV < smax) ? BIGV : oa0;
    }

    if (anyflag) {                    // cold exact fallback (block-uniform)
        for (int i = tid; i < M_; i += 512) {
            sk[i] = (i < N_) ? expf(x[b * N_ + i] * 1.79f) : __builtin_inff();
            sv[i] = i;
        }
        __syncthreads();
        for (int k = 2; k <= M_; k <<= 1) {
            for (int j = k >> 1; j > 0; j >>= 1) {
                int i = ((tid & ~(j - 1)) << 1) | (tid & (j - 1));
                int p = i | j;
                float ki = sk[i], kp = sk[p];
                int   vi = sv[i], vp = sv[p];
                bool gt = (ki > kp) || (ki == kp && vi > vp);
                bool up = ((i & k) == 0);
                if (gt == up) { sk[i] = kp; sk[p] = ki; sv[i] = vp; sv[p] = vi; }
                __syncthreads();
            }
        }
        if (fl) {
            const float* wrow = w + (size_t)tid * N_;
            float w0   = wrow[sv[0]];
            float mul0 = sk[0] * w0;
            float den0 = fminf(fmaxf(w0 - 1.0f, 1e-10f), BIGV);
            float oa0  = mul0 / den0;
            bool found = (oa0 < __builtin_inff()) && (w0 > 1.0f);
            float res  = oa0;
            float wprev = w0, mulprev = mul0;
            for (int j = 1; j < N_; ++j) {
                float wj   = wrow[sv[j]];
                float sj   = sk[j];
                float mulj = sj * wj;
                float ws   = wj + wprev;
                float wim  = mulj + mulprev;
                float den  = fminf(fmaxf(ws - 1.0f, 1e-10f), BIGV);
                float oa   = wim / den;
                bool cond  = (oa < sk[j - 1]) && (ws > 1.0f);
                if (cond && !found) { res = oa; found = true; }
                wprev = wj; mulprev = mulj;
            }
            if (!found && BIGV < smax) res = BIGV;
            out[b * O_ + tid] = res;
        }
    }
}

extern "C" void kernel_launch(void* const* d_in, const int* in_sizes, int n_in,
                              void* d_out, int out_size, void* d_ws, size_t ws_size,
                              hipStream_t stream)
{
    const float* x = (const float*)d_in[0];   // [B, N]
    const float* w = (const float*)d_in[1];   // [O, N]
    float* out = (float*)d_out;               // [B, O]

    char* ws = (char*)d_ws;
    size_t off = 0;
    int*   fl   = (int*)  (ws + off); off += (size_t)O_ * sizeof(int);
    float* s0g  = (float*)(ws + off); off += (size_t)B_ * sizeof(float);
    int*   i0g  = (int*)  (ws + off); off += (size_t)B_ * sizeof(int);
    float* smxg = (float*)(ws + off); off += (size_t)B_ * sizeof(float);

    hipLaunchKernelGGL(snn_prep, dim3(128), dim3(512), 0, stream,
                       x, w, fl, s0g, i0g, smxg);
    hipLaunchKernelGGL(snn_out, dim3(B_), dim3(512), 0, stream,
                       x, w, fl, s0g, i0g, smxg, out);
}